// Round 6
// baseline (116.611 us; speedup 1.0000x reference)
//
#include <hip/hip_runtime.h>

#define HW    262144      // 512*512
#define BNUM  4
#define NC    33          // labels 0..32
#define NI    32          // instance channels

#define NB     1024       // t-space bins
#define BSCALE 64.0f      // NB / TMAX (TMAX = 16)
#define EG     4096       // e-grid bins in scan
#define ESCALE 2048.0f    // EG / 2.0

#define HSTR  1025        // sub-hist stride (odd => banks (s+ib)%32, full spread)
#define HWORDS (8 * HSTR) // 8200 words = 32.8 KB

typedef unsigned long long ull;

// ws layout in 32-bit words:
//   [0 .. 8192)    t-hist: u64[NB] per sample (sample s at ull index s*NB)
//   [8192..8196)   cntB[s]  K2 hist arrival counters
//   [8196]         cntF     finalize counter
//   [8200..8204)   fin[s]   per-sample losses
//   [8204..8208)   vart[s]  pooled variance term (written by cons_kernel)
//   [8208..8736)   cons float4[s][NC]
//   [8736.. )      partials float[s][128][168]
#define W_CNTB 8192
#define W_CNTF 8196
#define W_FINL 8200
#define W_VART 8204
#define W_CONS 8208
#define W_PART 8736
#define PJ 168            // padded words per block slot (165 used)
#define PS (128 * PJ)     // words per sample

// ---------------- K1: per-instance stats -> deterministic partials.
// Also zeroes t-hist + counters (no separate memset dispatch).
__global__ void __launch_bounds__(256) stats_kernel(
    const float* __restrict__ emb, const float* __restrict__ sig,
    const int* __restrict__ gt, float* __restrict__ ws) {
  int s = blockIdx.y;          // sample
  int j = blockIdx.x;          // 0..127 block within sample
  int t = threadIdx.x;
  int w = t >> 6;
  __shared__ float acc[4][165];   // [wave][f*33+n], f: e0,e1,ss,ss2,cnt
  int bid = s * 128 + j;          // 0..511
  unsigned* wsu = (unsigned*)ws;
  if (t < 16) {
    wsu[bid * 16 + t] = 0u;                  // 512*16 = 8192 words of t-hist
    if (bid == 0) wsu[8192 + t] = 0u;        // counters + fin + vart
  }
  for (int k = t; k < 4 * 165; k += 256) ((float*)acc)[k] = 0.f;
  __syncthreads();
  const float* e0p = emb + (size_t)s * 2 * HW;
  const float* e1p = e0p + HW;
  const float* sp  = sig + (size_t)s * HW;
  const int*   gp  = gt  + (size_t)s * HW;
  #pragma unroll
  for (int i = 0; i < 2; ++i) {
    int idx = j * 2048 + i * 1024 + t * 4;
    int4   lb = *(const int4*)(gp + idx);
    float4 x  = *(const float4*)(e0p + idx);
    float4 y  = *(const float4*)(e1p + idx);
    float4 sg = *(const float4*)(sp + idx);
#define ACC(L, X, Y, SG)                                                   \
    if (L > 0) {                                                           \
      atomicAdd(&acc[w][L], X);        atomicAdd(&acc[w][33 + L], Y);      \
      atomicAdd(&acc[w][66 + L], SG);  atomicAdd(&acc[w][99 + L], (SG)*(SG)); \
      atomicAdd(&acc[w][132 + L], 1.0f);                                   \
    }
    ACC(lb.x, x.x, y.x, sg.x)
    ACC(lb.y, x.y, y.y, sg.y)
    ACC(lb.z, x.z, y.z, sg.z)
    ACC(lb.w, x.w, y.w, sg.w)
#undef ACC
  }
  __syncthreads();
  if (t < 165) {
    float v = acc[0][t] + acc[1][t] + acc[2][t] + acc[3][t];
    ws[W_PART + s * PS + j * PJ + t] = v;   // plain store, unique slot
  }
}

// ---------------- K1b: reduce partials ONCE per sample -> cons + vart.
// Kernel boundary provides coherence; no fences, deterministic sum order.
__global__ void __launch_bounds__(512) cons_kernel(float* __restrict__ ws) {
  int s = blockIdx.x;
  int t = threadIdx.x;
  int lane = t & 63, wid = t >> 6;
  __shared__ float sums2[2][165];
  __shared__ float sums[165];
  if (t < 330) {
    int r = (t >= 165) ? 1 : 0;
    int c = t - r * 165;
    const float* pp = ws + W_PART + s * PS + (r << 6) * PJ + c;
    float sum = 0.f;
    #pragma unroll 16
    for (int jj = 0; jj < 64; ++jj) sum += pp[jj * PJ];
    sums2[r][c] = sum;
  }
  __syncthreads();
  if (t < 165) sums[t] = sums2[0][t] + sums2[1][t];
  __syncthreads();
  if (t >= 1 && t < NC) {
    float c = sums[132 + t];
    float4 C;
    if (c > 0.f) {
      float inv = 1.0f / c;
      float c0 = sums[t] * inv, c1 = sums[33 + t] * inv, sgm = sums[66 + t] * inv;
      float Q = 0.5f / (sgm * sgm) * BSCALE;
      C.x = Q; C.y = -2.0f * Q * c0; C.z = -2.0f * Q * c1;
      C.w = Q * (c0 * c0 + c1 * c1);
    } else {
      C.x = 0.f; C.y = 0.f; C.z = 0.f; C.w = (float)NB;  // last bin, e~0
    }
    ((float4*)(ws + W_CONS))[s * NC + t] = C;
  }
  if (wid == 0) {   // pooled variance: vart = S_total * (sum 1/c) / NI
    float S = 0.f, rcp = 0.f;
    if (lane >= 1 && lane < NC) {
      float c = sums[132 + lane];
      if (c > 0.f) {
        float sg = sums[66 + lane] / c;
        S = sums[99 + lane] - c * sg * sg;
        rcp = 1.0f / c;
      }
    }
    for (int o = 32; o; o >>= 1) {
      S   += __shfl_down(S, o);
      rcp += __shfl_down(rcp, o);
    }
    if (lane == 0) ws[W_VART + s] = S * rcp / (float)NI;
  }
}

// ---------------- K2: hist (8 odd-stride sub-hists) -> u64 flush; last block scans.
__global__ void __launch_bounds__(512) hist_scan_kernel(
    const float* __restrict__ emb, const int* __restrict__ gt,
    float* __restrict__ ws, float* __restrict__ out) {
  int s  = blockIdx.y;
  int lb = blockIdx.x;           // 0..127
  __shared__ unsigned hist[HWORDS];   // 32.8 KB; aliased as e-grid in tail
  __shared__ float4 cons[NC];
  __shared__ ull wsum[8];
  __shared__ float red[8];
  __shared__ int flag;
  int t = threadIdx.x;
  int lane = t & 63, wid = t >> 6;
  for (int k = t; k < HWORDS; k += 512) hist[k] = 0u;
  if (t < NC) cons[t] = ((const float4*)(ws + W_CONS))[s * NC + t];
  __syncthreads();
  const float* e0p = emb + (size_t)s * 2 * HW;
  const float* e1p = e0p + HW;
  const int*   gp  = gt  + (size_t)s * HW;
  int idx = lb * 2048 + t * 4;
  int4   lbl = *(const int4*)(gp + idx);
  float4 px  = *(const float4*)(e0p + idx);
  float4 py  = *(const float4*)(e1p + idx);
  float4 ss;
  ss.x = fmaf(px.x, px.x, py.x * py.x);
  ss.y = fmaf(px.y, px.y, py.y * py.y);
  ss.z = fmaf(px.z, px.z, py.z * py.z);
  ss.w = fmaf(px.w, px.w, py.w * py.w);
  // odd-stride sub-hist: bank of hr[ib] = ((t&7)*1025 + ib) % 32 = (s+ib)%32
  unsigned* hr = hist + (t & 7) * HSTR;
  // positive-item correction: the n-loop adds 1 (neg) for every item,
  // including the pixel's own instance; add 0xFFFF at the same bin so the
  // total becomes 0x10000 (one pos, zero neg) for the pos item.
#define POSFIX(P0, P1, SV, L)                                            \
    if (L > 0) {                                                         \
      float4 C = cons[L];                                                \
      float bf = fmaf(C.x, SV, fmaf(C.y, P0, fmaf(C.z, P1, C.w)));       \
      int ib = min((int)bf, NB - 1);                                     \
      atomicAdd(&hr[ib], 0xFFFFu);                                       \
    }
  POSFIX(px.x, py.x, ss.x, lbl.x)
  POSFIX(px.y, py.y, ss.y, lbl.y)
  POSFIX(px.z, py.z, ss.z, lbl.z)
  POSFIX(px.w, py.w, ss.w, lbl.w)
#undef POSFIX
  #pragma unroll 4
  for (int n = 1; n <= NI; ++n) {
    float4 C = cons[n];
    // branchless: clamp to last bin; far items land at e~2e-7, processed
    // last in the descending scan where p==P already -> contribution ~0.
#define ITEM(P0, P1, SV)                                               \
    {                                                                  \
      float bf = fmaf(C.x, SV, fmaf(C.y, P0, fmaf(C.z, P1, C.w)));     \
      int ib = min((int)bf, NB - 1);                                   \
      atomicAdd(&hr[ib], 1u);                                          \
    }
    ITEM(px.x, py.x, ss.x)
    ITEM(px.y, py.y, ss.y)
    ITEM(px.z, py.z, ss.z)
    ITEM(px.w, py.w, ss.w)
#undef ITEM
  }
  __syncthreads();
  // flush to the sample's global t-hist (device-scope u64 atomics: this
  // pre-merges across blocks so the tail reads only 8 KB)
  ull* th = ((ull*)ws) + (size_t)s * NB;
  for (int k = t; k < NB; k += 512) {
    unsigned v = 0;
    #pragma unroll
    for (int sh = 0; sh < 8; ++sh) v += hist[sh * HSTR + k];
    if (v) {
      ull add = ((ull)(v >> 16) << 32) | (v & 0xFFFFu);
      atomicAdd(&th[k], add);
    }
  }
  __syncthreads();
  if (t == 0) {
    __threadfence();   // release our (atomic) flush before arrival
    flag = (atomicAdd((unsigned*)ws + W_CNTB + s, 1u) == 127u);
  }
  __syncthreads();
  if (!flag) return;

  // ================= scan phase (one block per sample) =================
  __threadfence();   // acquire: invalidate L1/L2 so plain loads see remote atomics
  unsigned* ep = hist;
  unsigned* en = hist + EG;
  for (int k = t; k < 2 * EG; k += 512) hist[k] = 0u;
  float vart = ws[W_VART + s];
  __syncthreads();
  // read global t-hist: coalesced plain uint4 (2 bins/thread), scatter to e-grid
  {
    uint4 v = *(const uint4*)(th + 2 * t);
    #pragma unroll
    for (int h = 0; h < 2; ++h) {
      int b = 2 * t + h;
      unsigned neg = h ? v.z : v.x;     // u64 little-endian: low=neg, high=pos
      unsigned pos = h ? v.w : v.y;
      if (pos | neg) {
        float tc = ((float)b + 0.5f) * (1.0f / BSCALE);
        float ex = __expf(-tc);
        if (pos) {
          float e = 2.0f - 2.0f * ex;
          int k = (int)(e * ESCALE); if (k > EG - 1) k = EG - 1;
          atomicAdd(&ep[k], pos);
        }
        if (neg) {
          float e = 2.0f * ex;
          int k = (int)(e * ESCALE); if (k > EG - 1) k = EG - 1;
          atomicAdd(&en[k], neg);
        }
      }
    }
  }
  __syncthreads();
  const int CH = EG / 512;  // 8
  int j0 = t * CH;
  unsigned np = 0, nn = 0;
  for (int k = 0; k < CH; ++k) {
    int b = EG - 1 - (j0 + k);
    np += ep[b]; nn += en[b];
  }
  ull v = ((ull)np << 32) | (ull)nn;
  ull inc = v;
  for (int o = 1; o < 64; o <<= 1) {
    ull u = __shfl_up(inc, o);
    if (lane >= o) inc += u;
  }
  if (lane == 63) wsum[wid] = inc;
  __syncthreads();
  ull offset = 0, total = 0;
  for (int i = 0; i < 8; ++i) {
    ull xr = wsum[i];
    if (i < wid) offset += xr;
    total += xr;
  }
  ull excl = offset + inc - v;
  float P = (float)(unsigned)(total >> 32);
  unsigned p = (unsigned)(excl >> 32), f = (unsigned)(excl & 0xFFFFFFFFu);
  float jprev = 1.0f - (P - (float)p) / (P + (float)f);
  float contrib = 0.f;
  for (int k = 0; k < CH; ++k) {
    int b = EG - 1 - (j0 + k);
    unsigned ap_ = ep[b], an_ = en[b];
    if (ap_ | an_) {
      p += ap_; f += an_;
      float j = 1.0f - (P - (float)p) / (P + (float)f);
      float e = ((float)b + 0.5f) * (2.0f / EG);
      contrib += e * (j - jprev);
      jprev = j;
    }
  }
  for (int o = 32; o; o >>= 1) contrib += __shfl_down(contrib, o);
  if (lane == 0) red[wid] = contrib;
  __syncthreads();
  if (t == 0) {
    float tot = 0.f;
    for (int i = 0; i < 8; ++i) tot += red[i];
    float loss = tot + vart;
    float* fin = ws + W_FINL;
    atomicExch(&fin[s], loss);
    __threadfence();
    unsigned old = atomicAdd((unsigned*)ws + W_CNTF, 1u);
    if (old == BNUM - 1) {
      float a = 0.f;
      for (int i = 0; i < BNUM; ++i) a += atomicAdd(&fin[i], 0.0f);
      out[0] = a * (1.0f / BNUM);
    }
  }
}

extern "C" void kernel_launch(void* const* d_in, const int* in_sizes, int n_in,
                              void* d_out, int out_size, void* d_ws, size_t ws_size,
                              hipStream_t stream) {
  const float* emb = (const float*)d_in[0];   // [4,2,512,512]
  const float* sig = (const float*)d_in[1];   // [4,1,512,512]
  const int*   gt  = (const int*)d_in[2];     // [4,1,512,512]
  float* out = (float*)d_out;
  float* ws  = (float*)d_ws;

  dim3 gA(128, BNUM);
  stats_kernel<<<gA, 256, 0, stream>>>(emb, sig, gt, ws);
  cons_kernel<<<BNUM, 512, 0, stream>>>(ws);
  dim3 gB(128, BNUM);
  hist_scan_kernel<<<gB, 512, 0, stream>>>(emb, gt, ws, out);
}

// Round 7
// 113.894 us; speedup vs baseline: 1.0239x; 1.0239x over previous
//
#include <hip/hip_runtime.h>

#define HW    262144      // 512*512
#define BNUM  4
#define NC    33          // labels 0..32
#define NI    32          // instance channels

#define NB     1024       // t-space bins
#define BSCALE 64.0f      // NB / TMAX (TMAX = 16)
#define EG     4096       // e-grid bins in scan
#define ESCALE 2048.0f    // EG / 2.0

typedef unsigned long long ull;

// ws layout in 32-bit words:
//   [0 .. 8192)    t-hist: u64[NB] per sample (sample s at ull index s*NB)
//   [8192..8196)   cntB[s]  K2 hist arrival counters
//   [8196]         cntF     finalize counter
//   [8200..8204)   fin[s]   per-sample losses
//   [8204..8208)   vart[s]  pooled variance term (written by cons_kernel)
//   [8208..8736)   cons float4[s][NC]
//   [8736.. )      partials float[s][128][168]
#define W_CNTB 8192
#define W_CNTF 8196
#define W_FINL 8200
#define W_VART 8204
#define W_CONS 8208
#define W_PART 8736
#define PJ 168            // padded words per block slot (165 used)
#define PS (128 * PJ)     // words per sample

// ---------------- K1: per-instance stats -> deterministic partials.
// Also zeroes t-hist + counters (no separate memset dispatch).
__global__ void __launch_bounds__(256) stats_kernel(
    const float* __restrict__ emb, const float* __restrict__ sig,
    const int* __restrict__ gt, float* __restrict__ ws) {
  int s = blockIdx.y;          // sample
  int j = blockIdx.x;          // 0..127 block within sample
  int t = threadIdx.x;
  int w = t >> 6;
  __shared__ float acc[4][165];   // [wave][f*33+n], f: e0,e1,ss,ss2,cnt
  int bid = s * 128 + j;          // 0..511
  unsigned* wsu = (unsigned*)ws;
  const float* e0p = emb + (size_t)s * 2 * HW;
  const float* e1p = e0p + HW;
  const float* sp  = sig + (size_t)s * HW;
  const int*   gp  = gt  + (size_t)s * HW;
  // prefetch: issue ALL input loads before LDS init so HBM latency hides
  int idx0 = j * 2048 + t * 4;
  int idx1 = idx0 + 1024;
  int4   lb0 = *(const int4*)(gp + idx0);
  int4   lb1 = *(const int4*)(gp + idx1);
  float4 x0  = *(const float4*)(e0p + idx0);
  float4 x1  = *(const float4*)(e0p + idx1);
  float4 y0  = *(const float4*)(e1p + idx0);
  float4 y1  = *(const float4*)(e1p + idx1);
  float4 sg0 = *(const float4*)(sp + idx0);
  float4 sg1 = *(const float4*)(sp + idx1);
  if (t < 16) {
    wsu[bid * 16 + t] = 0u;                  // 512*16 = 8192 words of t-hist
    if (bid == 0) wsu[8192 + t] = 0u;        // counters + fin + vart
  }
  for (int k = t; k < 4 * 165; k += 256) ((float*)acc)[k] = 0.f;
  __syncthreads();
#define ACC(L, X, Y, SG)                                                   \
    if (L > 0) {                                                           \
      atomicAdd(&acc[w][L], X);        atomicAdd(&acc[w][33 + L], Y);      \
      atomicAdd(&acc[w][66 + L], SG);  atomicAdd(&acc[w][99 + L], (SG)*(SG)); \
      atomicAdd(&acc[w][132 + L], 1.0f);                                   \
    }
  ACC(lb0.x, x0.x, y0.x, sg0.x)
  ACC(lb0.y, x0.y, y0.y, sg0.y)
  ACC(lb0.z, x0.z, y0.z, sg0.z)
  ACC(lb0.w, x0.w, y0.w, sg0.w)
  ACC(lb1.x, x1.x, y1.x, sg1.x)
  ACC(lb1.y, x1.y, y1.y, sg1.y)
  ACC(lb1.z, x1.z, y1.z, sg1.z)
  ACC(lb1.w, x1.w, y1.w, sg1.w)
#undef ACC
  __syncthreads();
  if (t < 165) {
    float v = acc[0][t] + acc[1][t] + acc[2][t] + acc[3][t];
    ws[W_PART + s * PS + j * PJ + t] = v;   // plain store, unique slot
  }
}

// ---------------- K1b: reduce partials ONCE per sample -> cons + vart.
// Kernel boundary provides coherence; no fences, deterministic sum order.
__global__ void __launch_bounds__(512) cons_kernel(float* __restrict__ ws) {
  int s = blockIdx.x;
  int t = threadIdx.x;
  int lane = t & 63, wid = t >> 6;
  __shared__ float sums2[2][165];
  __shared__ float sums[165];
  if (t < 330) {
    int r = (t >= 165) ? 1 : 0;
    int c = t - r * 165;
    const float* pp = ws + W_PART + s * PS + (r << 6) * PJ + c;
    float sum = 0.f;
    #pragma unroll 16
    for (int jj = 0; jj < 64; ++jj) sum += pp[jj * PJ];
    sums2[r][c] = sum;
  }
  __syncthreads();
  if (t < 165) sums[t] = sums2[0][t] + sums2[1][t];
  __syncthreads();
  if (t >= 1 && t < NC) {
    float c = sums[132 + t];
    float4 C;
    if (c > 0.f) {
      float inv = 1.0f / c;
      float c0 = sums[t] * inv, c1 = sums[33 + t] * inv, sgm = sums[66 + t] * inv;
      float Q = 0.5f / (sgm * sgm) * BSCALE;
      C.x = Q; C.y = -2.0f * Q * c0; C.z = -2.0f * Q * c1;
      C.w = Q * (c0 * c0 + c1 * c1);
    } else {
      C.x = 0.f; C.y = 0.f; C.z = 0.f; C.w = (float)NB;  // last bin, e~0
    }
    ((float4*)(ws + W_CONS))[s * NC + t] = C;
  }
  if (wid == 0) {   // pooled variance: vart = S_total * (sum 1/c) / NI
    float S = 0.f, rcp = 0.f;
    if (lane >= 1 && lane < NC) {
      float c = sums[132 + lane];
      if (c > 0.f) {
        float sg = sums[66 + lane] / c;
        S = sums[99 + lane] - c * sg * sg;
        rcp = 1.0f / c;
      }
    }
    for (int o = 32; o; o >>= 1) {
      S   += __shfl_down(S, o);
      rcp += __shfl_down(rcp, o);
    }
    if (lane == 0) ws[W_VART + s] = S * rcp / (float)NI;
  }
}

// ---------------- K2: hist (8 sub-hists, 64 blocks/sample) -> u64 flush;
// last-arriving block per sample scans.
__global__ void __launch_bounds__(512) hist_scan_kernel(
    const float* __restrict__ emb, const int* __restrict__ gt,
    float* __restrict__ ws, float* __restrict__ out) {
  int s  = blockIdx.y;
  int lb = blockIdx.x;           // 0..63
  __shared__ unsigned hist[NB * 8];   // 32 KB; 8 sub-hists, aliased e-grid in tail
  __shared__ float4 cons[NC];
  __shared__ ull wsum[8];
  __shared__ float red[8];
  __shared__ int flag;
  int t = threadIdx.x;
  int lane = t & 63, wid = t >> 6;
  const float* e0p = emb + (size_t)s * 2 * HW;
  const float* e1p = e0p + HW;
  const int*   gp  = gt  + (size_t)s * HW;
  // prefetch: 8 px/thread, all loads issued before LDS init (latency hidden)
  int base = lb * 4096 + t * 4;
  int4   lbl0 = *(const int4*)(gp + base);
  int4   lbl1 = *(const int4*)(gp + base + 2048);
  float4 px0  = *(const float4*)(e0p + base);
  float4 px1  = *(const float4*)(e0p + base + 2048);
  float4 py0  = *(const float4*)(e1p + base);
  float4 py1  = *(const float4*)(e1p + base + 2048);
  for (int k = t; k < NB * 8; k += 512) hist[k] = 0u;
  if (t < NC) cons[t] = ((const float4*)(ws + W_CONS))[s * NC + t];
  float4 ss0, ss1;
  ss0.x = fmaf(px0.x, px0.x, py0.x * py0.x);
  ss0.y = fmaf(px0.y, px0.y, py0.y * py0.y);
  ss0.z = fmaf(px0.z, px0.z, py0.z * py0.z);
  ss0.w = fmaf(px0.w, px0.w, py0.w * py0.w);
  ss1.x = fmaf(px1.x, px1.x, py1.x * py1.x);
  ss1.y = fmaf(px1.y, px1.y, py1.y * py1.y);
  ss1.z = fmaf(px1.z, px1.z, py1.z * py1.z);
  ss1.w = fmaf(px1.w, px1.w, py1.w * py1.w);
  __syncthreads();
  unsigned* hr = hist + (t & 7);
  // positive-item correction: the n-loop adds 1 (neg) for every item,
  // including the pixel's own instance; add 0xFFFF at the same bin so the
  // total becomes 0x10000 (one pos, zero neg) for the pos item.
#define POSFIX(P0, P1, SV, L)                                            \
    if (L > 0) {                                                         \
      float4 C = cons[L];                                                \
      float bf = fmaf(C.x, SV, fmaf(C.y, P0, fmaf(C.z, P1, C.w)));       \
      int ib = min((int)bf, NB - 1);                                     \
      atomicAdd(&hr[ib << 3], 0xFFFFu);                                  \
    }
  POSFIX(px0.x, py0.x, ss0.x, lbl0.x)
  POSFIX(px0.y, py0.y, ss0.y, lbl0.y)
  POSFIX(px0.z, py0.z, ss0.z, lbl0.z)
  POSFIX(px0.w, py0.w, ss0.w, lbl0.w)
  POSFIX(px1.x, py1.x, ss1.x, lbl1.x)
  POSFIX(px1.y, py1.y, ss1.y, lbl1.y)
  POSFIX(px1.z, py1.z, ss1.z, lbl1.z)
  POSFIX(px1.w, py1.w, ss1.w, lbl1.w)
#undef POSFIX
  #pragma unroll 4
  for (int n = 1; n <= NI; ++n) {
    float4 C = cons[n];
    // branchless: clamp to last bin; far items land at e~2e-7, processed
    // last in the descending scan where p==P already -> contribution ~0.
#define ITEM(P0, P1, SV)                                               \
    {                                                                  \
      float bf = fmaf(C.x, SV, fmaf(C.y, P0, fmaf(C.z, P1, C.w)));     \
      int ib = min((int)bf, NB - 1);                                   \
      atomicAdd(&hr[ib << 3], 1u);                                     \
    }
    ITEM(px0.x, py0.x, ss0.x)
    ITEM(px0.y, py0.y, ss0.y)
    ITEM(px0.z, py0.z, ss0.z)
    ITEM(px0.w, py0.w, ss0.w)
    ITEM(px1.x, py1.x, ss1.x)
    ITEM(px1.y, py1.y, ss1.y)
    ITEM(px1.z, py1.z, ss1.z)
    ITEM(px1.w, py1.w, ss1.w)
#undef ITEM
  }
  __syncthreads();
  // flush to the sample's global t-hist (device-scope u64 atomics: this
  // pre-merges across blocks so the tail reads only 8 KB); 64 blocks/sample
  // halves the atomic count and contention vs 128.
  ull* th = ((ull*)ws) + (size_t)s * NB;
  for (int k = t; k < NB; k += 512) {
    uint4 a = *(uint4*)&hist[k * 8];
    uint4 b = *(uint4*)&hist[k * 8 + 4];
    unsigned v = a.x + a.y + a.z + a.w + b.x + b.y + b.z + b.w;
    if (v) {
      ull add = ((ull)(v >> 16) << 32) | (v & 0xFFFFu);
      atomicAdd(&th[k], add);
    }
  }
  __syncthreads();
  if (t == 0) {
    __threadfence();   // release our (atomic) flush before arrival
    flag = (atomicAdd((unsigned*)ws + W_CNTB + s, 1u) == 63u);
  }
  __syncthreads();
  if (!flag) return;

  // ================= scan phase (one block per sample) =================
  unsigned* ep = hist;
  unsigned* en = hist + EG;
  for (int k = t; k < 2 * EG; k += 512) hist[k] = 0u;
  float vart = ws[W_VART + s];
  __syncthreads();
  // read global t-hist (atomic reads for cross-XCD coherence), scatter to e-grid
  for (int b = t; b < NB; b += 512) {
    ull v = atomicAdd(&th[b], 0ull);
    unsigned pos = (unsigned)(v >> 32), neg = (unsigned)(v & 0xFFFFFFFFu);
    if (pos | neg) {
      float tc = ((float)b + 0.5f) * (1.0f / BSCALE);
      float ex = __expf(-tc);
      if (pos) {
        float e = 2.0f - 2.0f * ex;
        int k = (int)(e * ESCALE); if (k > EG - 1) k = EG - 1;
        atomicAdd(&ep[k], pos);
      }
      if (neg) {
        float e = 2.0f * ex;
        int k = (int)(e * ESCALE); if (k > EG - 1) k = EG - 1;
        atomicAdd(&en[k], neg);
      }
    }
  }
  __syncthreads();
  const int CH = EG / 512;  // 8
  int j0 = t * CH;
  unsigned np = 0, nn = 0;
  for (int k = 0; k < CH; ++k) {
    int b = EG - 1 - (j0 + k);
    np += ep[b]; nn += en[b];
  }
  ull v = ((ull)np << 32) | (ull)nn;
  ull inc = v;
  for (int o = 1; o < 64; o <<= 1) {
    ull u = __shfl_up(inc, o);
    if (lane >= o) inc += u;
  }
  if (lane == 63) wsum[wid] = inc;
  __syncthreads();
  ull offset = 0, total = 0;
  for (int i = 0; i < 8; ++i) {
    ull xr = wsum[i];
    if (i < wid) offset += xr;
    total += xr;
  }
  ull excl = offset + inc - v;
  float P = (float)(unsigned)(total >> 32);
  unsigned p = (unsigned)(excl >> 32), f = (unsigned)(excl & 0xFFFFFFFFu);
  float jprev = 1.0f - (P - (float)p) / (P + (float)f);
  float contrib = 0.f;
  for (int k = 0; k < CH; ++k) {
    int b = EG - 1 - (j0 + k);
    unsigned ap_ = ep[b], an_ = en[b];
    if (ap_ | an_) {
      p += ap_; f += an_;
      float j = 1.0f - (P - (float)p) / (P + (float)f);
      float e = ((float)b + 0.5f) * (2.0f / EG);
      contrib += e * (j - jprev);
      jprev = j;
    }
  }
  for (int o = 32; o; o >>= 1) contrib += __shfl_down(contrib, o);
  if (lane == 0) red[wid] = contrib;
  __syncthreads();
  if (t == 0) {
    float tot = 0.f;
    for (int i = 0; i < 8; ++i) tot += red[i];
    float loss = tot + vart;
    float* fin = ws + W_FINL;
    atomicExch(&fin[s], loss);
    __threadfence();
    unsigned old = atomicAdd((unsigned*)ws + W_CNTF, 1u);
    if (old == BNUM - 1) {
      float a = 0.f;
      for (int i = 0; i < BNUM; ++i) a += atomicAdd(&fin[i], 0.0f);
      out[0] = a * (1.0f / BNUM);
    }
  }
}

extern "C" void kernel_launch(void* const* d_in, const int* in_sizes, int n_in,
                              void* d_out, int out_size, void* d_ws, size_t ws_size,
                              hipStream_t stream) {
  const float* emb = (const float*)d_in[0];   // [4,2,512,512]
  const float* sig = (const float*)d_in[1];   // [4,1,512,512]
  const int*   gt  = (const int*)d_in[2];     // [4,1,512,512]
  float* out = (float*)d_out;
  float* ws  = (float*)d_ws;

  dim3 gA(128, BNUM);
  stats_kernel<<<gA, 256, 0, stream>>>(emb, sig, gt, ws);
  cons_kernel<<<BNUM, 512, 0, stream>>>(ws);
  dim3 gB(64, BNUM);
  hist_scan_kernel<<<gB, 512, 0, stream>>>(emb, gt, ws, out);
}